// Round 9
// baseline (1357.847 us; speedup 1.0000x reference)
//
#include <hip/hip_runtime.h>

#define K_NN 20
#define NEG_INF (-__builtin_inff())

constexpr int BB   = 16;
constexpr int NN   = 2048;
constexpr int CATC = 512;                 // concat feature width
constexpr int ROW_G = BB * NN;            // 32768 points total

typedef short bf16x8 __attribute__((ext_vector_type(8)));   // 8 bf16 = 4 VGPR
typedef float f32x4  __attribute__((ext_vector_type(4)));

// ---------------- bf16 split helpers (hi = rn(a), lo = rn(a - hi)) ----------
__device__ __forceinline__ unsigned short f2bf_rn(float f) {
  unsigned int u = __float_as_uint(f);
  unsigned int r = u + 0x7FFFu + ((u >> 16) & 1u);
  return (unsigned short)(r >> 16);
}
__device__ __forceinline__ float bf2f(unsigned short h) {
  return __uint_as_float((unsigned int)h << 16);
}
__device__ __forceinline__ void split_store(float v, unsigned short* ph, unsigned short* pl) {
  const unsigned short h = f2bf_rn(v);
  *ph = h;
  *pl = f2bf_rn(v - bf2f(h));
}
__device__ __forceinline__ float join_hl(unsigned short h, unsigned short l) {
  return bf2f(h) + bf2f(l);
}

__device__ __forceinline__ int mbcnt(unsigned long long mask) {   // popc(mask & lanes_below)
  return __builtin_amdgcn_mbcnt_hi((unsigned int)(mask >> 32),
         __builtin_amdgcn_mbcnt_lo((unsigned int)mask, 0));
}

// ---------------------------------------------------------------------------
// Branch-free u32 top-20 VALUE network (desc, duplicates kept).
// ---------------------------------------------------------------------------
#define DECL_VALS(INIT) \
  unsigned int v0=INIT,v1=INIT,v2=INIT,v3=INIT,v4=INIT,v5=INIT,v6=INIT,v7=INIT, \
               v8=INIT,v9=INIT,v10=INIT,v11=INIT,v12=INIT,v13=INIT,v14=INIT,    \
               v15=INIT,v16=INIT,v17=INIT,v18=INIT,v19=INIT;

#define INSERT_VAL(x) do {                         \
    v19 = min(v18, max(v19, (x)));                 \
    v18 = min(v17, max(v18, (x)));                 \
    v17 = min(v16, max(v17, (x)));                 \
    v16 = min(v15, max(v16, (x)));                 \
    v15 = min(v14, max(v15, (x)));                 \
    v14 = min(v13, max(v14, (x)));                 \
    v13 = min(v12, max(v13, (x)));                 \
    v12 = min(v11, max(v12, (x)));                 \
    v11 = min(v10, max(v11, (x)));                 \
    v10 = min(v9,  max(v10, (x)));                 \
    v9  = min(v8,  max(v9,  (x)));                 \
    v8  = min(v7,  max(v8,  (x)));                 \
    v7  = min(v6,  max(v7,  (x)));                 \
    v6  = min(v5,  max(v6,  (x)));                 \
    v5  = min(v4,  max(v5,  (x)));                 \
    v4  = min(v3,  max(v4,  (x)));                 \
    v3  = min(v2,  max(v3,  (x)));                 \
    v2  = min(v1,  max(v2,  (x)));                 \
    v1  = min(v0,  max(v1,  (x)));                 \
    v0  = max(v0, (x));                            \
  } while (0)

__device__ __forceinline__ unsigned int sortable(float d) {
  unsigned int ub = __float_as_uint(d);
  return (ub & 0x80000000u) ? ~ub : (ub | 0x80000000u);
}

// ---------------------------------------------------------------------------
// kNN stage 1: per (batch, row-tile 128, candidate-chunk 256) top-20 values.
// ---------------------------------------------------------------------------
__global__ __launch_bounds__(128) void knn_chunk_kernel(const float* __restrict__ x,
                                                        unsigned int* __restrict__ cv) {
  __shared__ float4 cand[256];           // {x, y, z, sq} per candidate
  const int bid = blockIdx.x;
  const int ch = bid & 7;          // candidate chunk (8 x 256)
  const int rt = (bid >> 3) & 15;  // row tile (16 x 128)
  const int b  = bid >> 7;         // batch
  const float* xb = x + (size_t)b * NN * 3;

  for (int i = threadIdx.x; i < 256; i += 128) {
    const int m = ch * 256 + i;
    const float px = xb[m*3+0], py = xb[m*3+1], pz = xb[m*3+2];
    cand[i] = make_float4(px, py, pz, fmaf(pz, pz, fmaf(py, py, px*px)));
  }
  __syncthreads();

  const int n = rt * 128 + threadIdx.x;
  const float cx = xb[n*3+0], cy = xb[n*3+1], cz = xb[n*3+2];
  const float csq = fmaf(cz, cz, fmaf(cy, cy, cx*cx));

  DECL_VALS(0u)

#pragma unroll 4
  for (int i = 0; i < 256; ++i) {
    const float4 c = cand[i];
    const float inner = fmaf(cz, c.z, fmaf(cy, c.y, cx*c.x));
    const float d = 2.0f * inner - csq - c.w;      // same op order as reference
    const unsigned int u = sortable(d);
    INSERT_VAL(u);
  }

  const int rowg = b * NN + n;
#define STORE_VAL(i) cv[(size_t)(ch*K_NN + i) * ROW_G + rowg] = v##i;
  STORE_VAL(0) STORE_VAL(1) STORE_VAL(2) STORE_VAL(3) STORE_VAL(4)
  STORE_VAL(5) STORE_VAL(6) STORE_VAL(7) STORE_VAL(8) STORE_VAL(9)
  STORE_VAL(10) STORE_VAL(11) STORE_VAL(12) STORE_VAL(13) STORE_VAL(14)
  STORE_VAL(15) STORE_VAL(16) STORE_VAL(17) STORE_VAL(18) STORE_VAL(19)
#undef STORE_VAL
}

// ---------------------------------------------------------------------------
// kNN stage 2a: merge 8 chunk value-lists -> d20 (20th-largest) per row.
// ---------------------------------------------------------------------------
__global__ __launch_bounds__(64) void knn_d20_kernel(const unsigned int* __restrict__ cv,
                                                     unsigned int* __restrict__ d20g) {
  const int r = blockIdx.x * 64 + threadIdx.x;
#define LOAD_VAL(i) unsigned int v##i = cv[(size_t)i * ROW_G + r];
  LOAD_VAL(0) LOAD_VAL(1) LOAD_VAL(2) LOAD_VAL(3) LOAD_VAL(4)
  LOAD_VAL(5) LOAD_VAL(6) LOAD_VAL(7) LOAD_VAL(8) LOAD_VAL(9)
  LOAD_VAL(10) LOAD_VAL(11) LOAD_VAL(12) LOAD_VAL(13) LOAD_VAL(14)
  LOAD_VAL(15) LOAD_VAL(16) LOAD_VAL(17) LOAD_VAL(18) LOAD_VAL(19)
#undef LOAD_VAL
#pragma unroll 4
  for (int i = K_NN; i < 8 * K_NN; ++i)
    INSERT_VAL(cv[(size_t)i * ROW_G + r]);
  d20g[r] = v19;
}

// ---------------------------------------------------------------------------
// kNN stage 2b: ONE WAVE PER ROW. Rescan 2048 candidates (64/iter), compact
// members (dist > d20, <=19 of them) via ballot; ties (== d20) appended in
// ascending index order (k-major x lane order) -> exact top_k membership.
// ---------------------------------------------------------------------------
__global__ __launch_bounds__(256) void knn_collect_kernel(const float* __restrict__ x,
    const unsigned int* __restrict__ d20g, int* __restrict__ idx_out) {
  __shared__ float4 cand[NN];            // 32 KB, one batch
  __shared__ int tie[4][K_NN];
  const int w = threadIdx.x >> 6, lane = threadIdx.x & 63;
  const int r = blockIdx.x * 4 + w;      // 4 consecutive rows = same batch
  const int b = r >> 11;
  const float* xb = x + (size_t)b * NN * 3;

  for (int i = threadIdx.x; i < NN; i += 256) {
    const float px = xb[i*3+0], py = xb[i*3+1], pz = xb[i*3+2];
    cand[i] = make_float4(px, py, pz, fmaf(pz, pz, fmaf(py, py, px*px)));
  }
  __syncthreads();

  const int n = r & (NN - 1);
  const float4 ctr = cand[n];            // ctr.w == csq, bit-identical to stage 1
  const unsigned int d20 = d20g[r];
  int* op = idx_out + (size_t)r * K_NN;
  int cg = 0, ce = 0;

#pragma unroll 4
  for (int k = 0; k < NN / 64; ++k) {
    const int i = k * 64 + lane;
    const float4 c = cand[i];
    const float inner = fmaf(ctr.z, c.z, fmaf(ctr.y, c.y, ctr.x*c.x));
    const float d = 2.0f * inner - ctr.w - c.w;    // bit-identical to stage 1
    const unsigned int u = sortable(d);
    const unsigned long long mb = __ballot(u > d20);
    if (u > d20) op[cg + mbcnt(mb)] = i;
    cg += __popcll(mb);
    const unsigned long long tb = __ballot(u == d20);
    if (tb) {
      if (u == d20) {
        const int pos = ce + mbcnt(tb);
        if (pos < K_NN) tie[w][pos] = i;           // capped: only need <=20
      }
      ce += __popcll(tb);
    }
  }
  if (lane == 0)
    for (int j = 0; cg < K_NN; ++j, ++cg) op[cg] = tie[w][j];
}

// ---------------------------------------------------------------------------
// EdgeConv -> split bf16 planes Ah/Al cols [0,64)
// ---------------------------------------------------------------------------
__global__ __launch_bounds__(256) void edgeconv_kernel(const float* __restrict__ x,
    const int* __restrict__ idx, const float* __restrict__ W0,
    const float* __restrict__ b0, unsigned short* __restrict__ Ahg,
    unsigned short* __restrict__ Alg) {
  const int o  = threadIdx.x & 63;
  const int pt = blockIdx.x * 4 + (threadIdx.x >> 6);
  const int b  = pt >> 11, n = pt & (NN - 1);
  const float* xb = x + (size_t)b * NN * 3;

  const float w0 = W0[o*6+0], w1 = W0[o*6+1], w2 = W0[o*6+2];
  const float w3 = W0[o*6+3], w4 = W0[o*6+4], w5 = W0[o*6+5];
  const float bias = b0[o];
  const float cx = xb[n*3+0], cy = xb[n*3+1], cz = xb[n*3+2];

  const int* ip = idx + (size_t)pt * K_NN;
  float px = 0.f, py = 0.f, pz = 0.f;
  if (o < K_NN) { const int m = ip[o]; px = xb[m*3+0]; py = xb[m*3+1]; pz = xb[m*3+2]; }

  float best = NEG_INF;
#pragma unroll
  for (int k = 0; k < K_NN; ++k) {
    const float ax = __shfl(px, k, 64), ay = __shfl(py, k, 64), az = __shfl(pz, k, 64);
    float h = w0 * (ax - cx);
    h = fmaf(w1, ay - cy, h);
    h = fmaf(w2, az - cz, h);
    h = fmaf(w3, cx, h);
    h = fmaf(w4, cy, h);
    h = fmaf(w5, cz, h);
    h += bias;
    h = (h > 0.f) ? h : 0.2f * h;
    best = fmaxf(best, h);
  }
  split_store(best, &Ahg[(size_t)pt * CATC + o], &Alg[(size_t)pt * CATC + o]);
}

// ---------------------------------------------------------------------------
// pool (max over kNN graph) + 1x1 conv + leaky relu.
// Round 9: keep round-8's vector gather + XCD-batch swizzle (FETCH 61.6->10MB
// verified) but restore occupancy: __launch_bounds__(256,4) caps VGPR at 128
// (round 8 hit 196 VGPR -> 11% occupancy -> latency-bound collapse), and
// neighbor-loop unroll 4 -> 2 (4 uint4 in flight instead of 8).
// ---------------------------------------------------------------------------
template<int CIN, int COUT, int PTS>
__global__ __launch_bounds__(256, 4) void pool_mlp_kernel(
    unsigned short* __restrict__ Ahg, unsigned short* __restrict__ Alg,
    const int* __restrict__ idx, const float* __restrict__ W,
    const float* __restrict__ bias, int coff_in, int coff_out) {
  __shared__ float pooled[PTS][CIN + 4];   // +4: 16B-aligned rows, bank spread
  __shared__ int sidx[PTS][K_NN];

  constexpr int BPB = NN / PTS;            // blocks per batch
  const int bid  = blockIdx.x;
  const int xcd  = bid & 7;
  const int s    = bid >> 3;
  const int b    = xcd * 2 + s / BPB;      // 2 batches per XCD
  const int inner= s % BPB;
  const int pt0  = b * NN + inner * PTS;

  for (int t = threadIdx.x; t < PTS * K_NN; t += 256)
    sidx[t / K_NN][t % K_NN] = idx[(size_t)pt0 * K_NN + t];
  __syncthreads();

  // ---- gather-max: 8 channels per thread, uint4 (bf16x8) loads ----
  constexpr int CG = CIN / 8;              // channel groups per point
  {
    const int p  = threadIdx.x / CG;
    const int c8 = threadIdx.x % CG;
    if (p < PTS) {
      const size_t base = (size_t)b * NN * CATC + coff_in + c8 * 8;
      float mv[8];
#pragma unroll
      for (int j = 0; j < 8; ++j) mv[j] = NEG_INF;
#pragma unroll 2
      for (int k = 0; k < K_NN; ++k) {
        const size_t a = base + (size_t)sidx[p][k] * CATC;
        const uint4 h = *(const uint4*)(Ahg + a);
        const uint4 l = *(const uint4*)(Alg + a);
        const unsigned int hw[4] = {h.x, h.y, h.z, h.w};
        const unsigned int lw[4] = {l.x, l.y, l.z, l.w};
#pragma unroll
        for (int q = 0; q < 4; ++q) {
          const float f0 = __uint_as_float(hw[q] << 16) + __uint_as_float(lw[q] << 16);
          const float f1 = __uint_as_float(hw[q] & 0xFFFF0000u) + __uint_as_float(lw[q] & 0xFFFF0000u);
          mv[2*q+0] = fmaxf(mv[2*q+0], f0);
          mv[2*q+1] = fmaxf(mv[2*q+1], f1);
        }
      }
      *(float4*)&pooled[p][c8 * 8]     = make_float4(mv[0], mv[1], mv[2], mv[3]);
      *(float4*)&pooled[p][c8 * 8 + 4] = make_float4(mv[4], mv[5], mv[6], mv[7]);
    }
  }
  __syncthreads();

  // ---- 1x1 conv + act + split store ----
  for (int t = threadIdx.x; t < PTS * COUT; t += 256) {
    const int p = t / COUT, o = t % COUT;
    const float4* pp = (const float4*)&pooled[p][0];
    const float4* wp = (const float4*)(W + (size_t)o * CIN);
    float acc = 0.f;
#pragma unroll
    for (int c4 = 0; c4 < CIN / 4; ++c4) {
      const float4 pv = pp[c4], wv = wp[c4];
      acc = fmaf(pv.x, wv.x, acc);
      acc = fmaf(pv.y, wv.y, acc);
      acc = fmaf(pv.z, wv.z, acc);
      acc = fmaf(pv.w, wv.w, acc);
    }
    float h = acc + bias[o];
    h = (h > 0.f) ? h : 0.2f * h;
    const size_t a = (size_t)(pt0 + p) * CATC + coff_out + o;
    split_store(h, &Ahg[a], &Alg[a]);
  }
}

// ---------------------------------------------------------------------------
// Split Wf (1024x512 f32) -> Wh, Wl bf16
// ---------------------------------------------------------------------------
__global__ __launch_bounds__(256) void wsplit_kernel(const float* __restrict__ Wf,
    unsigned short* __restrict__ Wh, unsigned short* __restrict__ Wl) {
  const int t = blockIdx.x * 256 + threadIdx.x;   // 131072 float4 groups
  const float4 v = ((const float4*)Wf)[t];
  ushort4 h4, l4;
  h4.x = f2bf_rn(v.x); l4.x = f2bf_rn(v.x - bf2f(h4.x));
  h4.y = f2bf_rn(v.y); l4.y = f2bf_rn(v.y - bf2f(h4.y));
  h4.z = f2bf_rn(v.z); l4.z = f2bf_rn(v.z - bf2f(h4.z));
  h4.w = f2bf_rn(v.w); l4.w = f2bf_rn(v.w - bf2f(h4.w));
  ((ushort4*)Wh)[t] = h4;
  ((ushort4*)Wl)[t] = l4;
}

// ---------------------------------------------------------------------------
// Final GEMM via bf16x3 MFMA: C = A.Wf^T, running max over rows -> partials.
// ---------------------------------------------------------------------------
__global__ __launch_bounds__(256) void final_gemm_mfma(
    const unsigned short* __restrict__ Ahg, const unsigned short* __restrict__ Alg,
    const unsigned short* __restrict__ Whg, const unsigned short* __restrict__ Wlg,
    float* __restrict__ partials) {
  __shared__ __align__(16) unsigned short AhL[128][40];
  __shared__ __align__(16) unsigned short AlL[128][40];
  __shared__ __align__(16) unsigned short WhL[128][40];
  __shared__ __align__(16) unsigned short WlL[128][40];

  // XCD-aware work decode: each XCD processes whole A-panels.
  const int L     = blockIdx.x + (blockIdx.y << 3) + (blockIdx.z << 7);  // 0..2047
  const int xcd   = L & 7;
  const int q     = L >> 3;        // 0..255
  const int ot    = q & 7;         // col tile, varies fastest within an XCD
  const int s     = q >> 3;        // 0..31 panel slot on this XCD
  const int p     = (s << 3) | xcd;  // panel 0..255
  const int chunk = p & 15;
  const int b     = p >> 4;

  const int tid   = threadIdx.x;
  const int lane  = tid & 63;
  const int w     = tid >> 6;      // wave 0..3
  const int wr    = w >> 1;        // row half (64)
  const int wc    = w & 1;         // col half (64)
  const int fr    = lane & 15;     // fragment row/col within 16
  const int kg    = lane >> 4;     // k-group 0..3

  const int srow = tid >> 1;
  const int shalf = (tid & 1) * 16;
  const size_t arow = ((size_t)(b * NN) + (size_t)chunk * 128 + srow) * CATC;
  const size_t wrow = ((size_t)ot * 128 + srow) * CATC;

  f32x4 acc[4][4];
#pragma unroll
  for (int i = 0; i < 4; ++i)
#pragma unroll
    for (int j = 0; j < 4; ++j) acc[i][j] = (f32x4){0.f, 0.f, 0.f, 0.f};

  // prologue: load tile 0 into named staging regs
  uint4 ra0 = *(const uint4*)(Ahg + arow + shalf);
  uint4 ra1 = *(const uint4*)(Ahg + arow + shalf + 8);
  uint4 ra2 = *(const uint4*)(Alg + arow + shalf);
  uint4 ra3 = *(const uint4*)(Alg + arow + shalf + 8);
  uint4 rw0 = *(const uint4*)(Whg + wrow + shalf);
  uint4 rw1 = *(const uint4*)(Whg + wrow + shalf + 8);
  uint4 rw2 = *(const uint4*)(Wlg + wrow + shalf);
  uint4 rw3 = *(const uint4*)(Wlg + wrow + shalf + 8);

  for (int kt = 0; kt < 16; ++kt) {
    __syncthreads();   // prior iteration's frag reads complete
    *(uint4*)&AhL[srow][shalf]     = ra0;
    *(uint4*)&AhL[srow][shalf + 8] = ra1;
    *(uint4*)&AlL[srow][shalf]     = ra2;
    *(uint4*)&AlL[srow][shalf + 8] = ra3;
    *(uint4*)&WhL[srow][shalf]     = rw0;
    *(uint4*)&WhL[srow][shalf + 8] = rw1;
    *(uint4*)&WlL[srow][shalf]     = rw2;
    *(uint4*)&WlL[srow][shalf + 8] = rw3;
    if (kt < 15) {     // prefetch next tile; latency hides under MFMA phase
      const int k0 = (kt + 1) * 32;
      ra0 = *(const uint4*)(Ahg + arow + k0 + shalf);
      ra1 = *(const uint4*)(Ahg + arow + k0 + shalf + 8);
      ra2 = *(const uint4*)(Alg + arow + k0 + shalf);
      ra3 = *(const uint4*)(Alg + arow + k0 + shalf + 8);
      rw0 = *(const uint4*)(Whg + wrow + k0 + shalf);
      rw1 = *(const uint4*)(Whg + wrow + k0 + shalf + 8);
      rw2 = *(const uint4*)(Wlg + wrow + k0 + shalf);
      rw3 = *(const uint4*)(Wlg + wrow + k0 + shalf + 8);
    }
    __syncthreads();

    bf16x8 ahf[4], alf[4], whf[4], wlf[4];
#pragma unroll
    for (int i = 0; i < 4; ++i) {
      ahf[i] = *(const bf16x8*)&AhL[wr * 64 + i * 16 + fr][kg * 8];
      alf[i] = *(const bf16x8*)&AlL[wr * 64 + i * 16 + fr][kg * 8];
    }
#pragma unroll
    for (int j = 0; j < 4; ++j) {
      whf[j] = *(const bf16x8*)&WhL[wc * 64 + j * 16 + fr][kg * 8];
      wlf[j] = *(const bf16x8*)&WlL[wc * 64 + j * 16 + fr][kg * 8];
    }

#pragma unroll
    for (int i = 0; i < 4; ++i)
#pragma unroll
      for (int j = 0; j < 4; ++j) {
        acc[i][j] = __builtin_amdgcn_mfma_f32_16x16x32_bf16(ahf[i], whf[j], acc[i][j], 0, 0, 0);
        acc[i][j] = __builtin_amdgcn_mfma_f32_16x16x32_bf16(ahf[i], wlf[j], acc[i][j], 0, 0, 0);
        acc[i][j] = __builtin_amdgcn_mfma_f32_16x16x32_bf16(alf[i], whf[j], acc[i][j], 0, 0, 0);
      }
  }

  // ---- epilogue: max over the wave's 64 rows per output col ----
  __syncthreads();                       // all LDS frag reads done
  float* smax = (float*)&AhL[0][0];      // reuse AhL as smax[2][128]
#pragma unroll
  for (int j = 0; j < 4; ++j) {
    float mj = NEG_INF;
#pragma unroll
    for (int i = 0; i < 4; ++i) {
      mj = fmaxf(mj, fmaxf(fmaxf(acc[i][j][0], acc[i][j][1]),
                           fmaxf(acc[i][j][2], acc[i][j][3])));
    }
    mj = fmaxf(mj, __shfl_xor(mj, 16, 64));
    mj = fmaxf(mj, __shfl_xor(mj, 32, 64));
    if (lane < 16) smax[wr * 128 + wc * 64 + j * 16 + fr] = mj;
  }
  __syncthreads();
  if (tid < 128) {
    const float m = fmaxf(smax[tid], smax[128 + tid]);
    partials[((size_t)(b * 16 + chunk)) * 1024 + (size_t)ot * 128 + tid] = m;
  }
}

__global__ __launch_bounds__(256) void final_reduce_kernel(const float* __restrict__ partials,
    const float* __restrict__ bf, float* __restrict__ out) {
  const int t = blockIdx.x * 256 + threadIdx.x;   // 16384
  const int b = t >> 10, o = t & 1023;
  float m = NEG_INF;
#pragma unroll
  for (int c = 0; c < 16; ++c)
    m = fmaxf(m, partials[((size_t)(b * 16 + c)) * 1024 + o]);
  float h = m + bf[o];
  out[t] = (h > 0.f) ? h : 0.2f * h;   // act(max+b) == max(act(.+b)) (monotone)
}

// ---------------------------------------------------------------------------
extern "C" void kernel_launch(void* const* d_in, const int* in_sizes, int n_in,
                              void* d_out, int out_size, void* d_ws, size_t ws_size,
                              hipStream_t stream) {
  (void)in_sizes; (void)n_in; (void)out_size; (void)ws_size;
  const float* x  = (const float*)d_in[0];
  const float* W0 = (const float*)d_in[1];
  const float* b0 = (const float*)d_in[2];
  const float* W1 = (const float*)d_in[3];
  const float* b1 = (const float*)d_in[4];
  const float* W2 = (const float*)d_in[5];
  const float* b2 = (const float*)d_in[6];
  const float* W3 = (const float*)d_in[7];
  const float* b3 = (const float*)d_in[8];
  const float* Wf = (const float*)d_in[9];
  const float* bf = (const float*)d_in[10];
  float* out = (float*)d_out;

  // ws layout (bytes), total 70,778,880:
  //   [0, 2621440)           : idx (int 32768x20) -- dead after pool3;
  //                            Wh [0,1MB) + Wl [1MB,2MB) alias (wsplit after pool3)
  //   [2621440, 23592960)    : cv (u32 160x32768) -- dead after d20, aliased under Ah
  //   [23592960, 23724032)   : d20 (u32 32768)    -- dead after collect, under Ah
  //   [2621440, 36175872)    : Ah bf16[32768][512] (written from edgeconv onward)
  //   [36175872, 69730304)   : Al bf16[32768][512]
  //   [69730304, 70778880)   : partials (float 16*16*1024)
  char* ws = (char*)d_ws;
  int* idx_ws = (int*)ws;
  unsigned short* Wh = (unsigned short*)ws;
  unsigned short* Wl = (unsigned short*)(ws + 1048576);
  unsigned int* cv = (unsigned int*)(ws + 2621440);
  unsigned int* d20g = (unsigned int*)(ws + 23592960);
  unsigned short* Ah = (unsigned short*)(ws + 2621440);
  unsigned short* Al = (unsigned short*)(ws + 36175872);
  float* partials = (float*)(ws + 69730304);

  knn_chunk_kernel<<<BB * 16 * 8, 128, 0, stream>>>(x, cv);
  knn_d20_kernel<<<ROW_G / 64, 64, 0, stream>>>(cv, d20g);
  knn_collect_kernel<<<ROW_G / 4, 256, 0, stream>>>(x, d20g, idx_ws);
  edgeconv_kernel<<<ROW_G / 4, 256, 0, stream>>>(x, idx_ws, W0, b0, Ah, Al);
  pool_mlp_kernel<64, 64, 32><<<BB * (NN / 32), 256, 0, stream>>>(Ah, Al, idx_ws, W1, b1, 0, 64);
  pool_mlp_kernel<64, 128, 32><<<BB * (NN / 32), 256, 0, stream>>>(Ah, Al, idx_ws, W2, b2, 64, 128);
  pool_mlp_kernel<128, 256, 16><<<BB * (NN / 16), 256, 0, stream>>>(Ah, Al, idx_ws, W3, b3, 128, 256);
  wsplit_kernel<<<512, 256, 0, stream>>>(Wf, Wh, Wl);
  final_gemm_mfma<<<dim3(8, 16, BB), 256, 0, stream>>>(Ah, Al, Wh, Wl, partials);
  final_reduce_kernel<<<BB * 1024 / 256, 256, 0, stream>>>(partials, bf, out);
}

// Round 11
// 497.562 us; speedup vs baseline: 2.7290x; 2.7290x over previous
//
#include <hip/hip_runtime.h>

#define K_NN 20
#define NEG_INF (-__builtin_inff())

constexpr int BB   = 16;
constexpr int NN   = 2048;
constexpr int CATC = 512;                 // concat feature width
constexpr int ROW_G = BB * NN;            // 32768 points total

typedef short bf16x8 __attribute__((ext_vector_type(8)));   // 8 bf16 = 4 VGPR
typedef float f32x4  __attribute__((ext_vector_type(4)));

// ---------------- bf16 split helpers (hi = rn(a), lo = rn(a - hi)) ----------
__device__ __forceinline__ unsigned short f2bf_rn(float f) {
  unsigned int u = __float_as_uint(f);
  unsigned int r = u + 0x7FFFu + ((u >> 16) & 1u);
  return (unsigned short)(r >> 16);
}
__device__ __forceinline__ float bf2f(unsigned short h) {
  return __uint_as_float((unsigned int)h << 16);
}
__device__ __forceinline__ void split_store(float v, unsigned short* ph, unsigned short* pl) {
  const unsigned short h = f2bf_rn(v);
  *ph = h;
  *pl = f2bf_rn(v - bf2f(h));
}

__device__ __forceinline__ int mbcnt(unsigned long long mask) {   // popc(mask & lanes_below)
  return __builtin_amdgcn_mbcnt_hi((unsigned int)(mask >> 32),
         __builtin_amdgcn_mbcnt_lo((unsigned int)mask, 0));
}

// ---------------------------------------------------------------------------
// Branch-free u32 top-20 VALUE network (desc, duplicates kept).
// ---------------------------------------------------------------------------
#define DECL_VALS(INIT) \
  unsigned int v0=INIT,v1=INIT,v2=INIT,v3=INIT,v4=INIT,v5=INIT,v6=INIT,v7=INIT, \
               v8=INIT,v9=INIT,v10=INIT,v11=INIT,v12=INIT,v13=INIT,v14=INIT,    \
               v15=INIT,v16=INIT,v17=INIT,v18=INIT,v19=INIT;

#define INSERT_VAL(x) do {                         \
    v19 = min(v18, max(v19, (x)));                 \
    v18 = min(v17, max(v18, (x)));                 \
    v17 = min(v16, max(v17, (x)));                 \
    v16 = min(v15, max(v16, (x)));                 \
    v15 = min(v14, max(v15, (x)));                 \
    v14 = min(v13, max(v14, (x)));                 \
    v13 = min(v12, max(v13, (x)));                 \
    v12 = min(v11, max(v12, (x)));                 \
    v11 = min(v10, max(v11, (x)));                 \
    v10 = min(v9,  max(v10, (x)));                 \
    v9  = min(v8,  max(v9,  (x)));                 \
    v8  = min(v7,  max(v8,  (x)));                 \
    v7  = min(v6,  max(v7,  (x)));                 \
    v6  = min(v5,  max(v6,  (x)));                 \
    v5  = min(v4,  max(v5,  (x)));                 \
    v4  = min(v3,  max(v4,  (x)));                 \
    v3  = min(v2,  max(v3,  (x)));                 \
    v2  = min(v1,  max(v2,  (x)));                 \
    v1  = min(v0,  max(v1,  (x)));                 \
    v0  = max(v0, (x));                            \
  } while (0)

__device__ __forceinline__ unsigned int sortable(float d) {
  unsigned int ub = __float_as_uint(d);
  return (ub & 0x80000000u) ? ~ub : (ub | 0x80000000u);
}

// ---------------------------------------------------------------------------
// kNN stage 1: per (batch, row-tile 128, candidate-chunk 256) top-20 values.
// ---------------------------------------------------------------------------
__global__ __launch_bounds__(128) void knn_chunk_kernel(const float* __restrict__ x,
                                                        unsigned int* __restrict__ cv) {
  __shared__ float4 cand[256];           // {x, y, z, sq} per candidate
  const int bid = blockIdx.x;
  const int ch = bid & 7;          // candidate chunk (8 x 256)
  const int rt = (bid >> 3) & 15;  // row tile (16 x 128)
  const int b  = bid >> 7;         // batch
  const float* xb = x + (size_t)b * NN * 3;

  for (int i = threadIdx.x; i < 256; i += 128) {
    const int m = ch * 256 + i;
    const float px = xb[m*3+0], py = xb[m*3+1], pz = xb[m*3+2];
    cand[i] = make_float4(px, py, pz, fmaf(pz, pz, fmaf(py, py, px*px)));
  }
  __syncthreads();

  const int n = rt * 128 + threadIdx.x;
  const float cx = xb[n*3+0], cy = xb[n*3+1], cz = xb[n*3+2];
  const float csq = fmaf(cz, cz, fmaf(cy, cy, cx*cx));

  DECL_VALS(0u)

#pragma unroll 4
  for (int i = 0; i < 256; ++i) {
    const float4 c = cand[i];
    const float inner = fmaf(cz, c.z, fmaf(cy, c.y, cx*c.x));
    const float d = 2.0f * inner - csq - c.w;      // same op order as reference
    const unsigned int u = sortable(d);
    INSERT_VAL(u);
  }

  const int rowg = b * NN + n;
#define STORE_VAL(i) cv[(size_t)(ch*K_NN + i) * ROW_G + rowg] = v##i;
  STORE_VAL(0) STORE_VAL(1) STORE_VAL(2) STORE_VAL(3) STORE_VAL(4)
  STORE_VAL(5) STORE_VAL(6) STORE_VAL(7) STORE_VAL(8) STORE_VAL(9)
  STORE_VAL(10) STORE_VAL(11) STORE_VAL(12) STORE_VAL(13) STORE_VAL(14)
  STORE_VAL(15) STORE_VAL(16) STORE_VAL(17) STORE_VAL(18) STORE_VAL(19)
#undef STORE_VAL
}

// ---------------------------------------------------------------------------
// kNN stage 2a: merge 8 chunk value-lists -> d20 (20th-largest) per row.
// ---------------------------------------------------------------------------
__global__ __launch_bounds__(64) void knn_d20_kernel(const unsigned int* __restrict__ cv,
                                                     unsigned int* __restrict__ d20g) {
  const int r = blockIdx.x * 64 + threadIdx.x;
#define LOAD_VAL(i) unsigned int v##i = cv[(size_t)i * ROW_G + r];
  LOAD_VAL(0) LOAD_VAL(1) LOAD_VAL(2) LOAD_VAL(3) LOAD_VAL(4)
  LOAD_VAL(5) LOAD_VAL(6) LOAD_VAL(7) LOAD_VAL(8) LOAD_VAL(9)
  LOAD_VAL(10) LOAD_VAL(11) LOAD_VAL(12) LOAD_VAL(13) LOAD_VAL(14)
  LOAD_VAL(15) LOAD_VAL(16) LOAD_VAL(17) LOAD_VAL(18) LOAD_VAL(19)
#undef LOAD_VAL
#pragma unroll 4
  for (int i = K_NN; i < 8 * K_NN; ++i)
    INSERT_VAL(cv[(size_t)i * ROW_G + r]);
  d20g[r] = v19;
}

// ---------------------------------------------------------------------------
// kNN stage 2b: ONE WAVE PER ROW. Rescan 2048 candidates (64/iter), compact
// members (dist > d20, <=19 of them) via ballot; ties (== d20) appended in
// ascending index order (k-major x lane order) -> exact top_k membership.
// ---------------------------------------------------------------------------
__global__ __launch_bounds__(256) void knn_collect_kernel(const float* __restrict__ x,
    const unsigned int* __restrict__ d20g, int* __restrict__ idx_out) {
  __shared__ float4 cand[NN];            // 32 KB, one batch
  __shared__ int tie[4][K_NN];
  const int w = threadIdx.x >> 6, lane = threadIdx.x & 63;
  const int r = blockIdx.x * 4 + w;      // 4 consecutive rows = same batch
  const int b = r >> 11;
  const float* xb = x + (size_t)b * NN * 3;

  for (int i = threadIdx.x; i < NN; i += 256) {
    const float px = xb[i*3+0], py = xb[i*3+1], pz = xb[i*3+2];
    cand[i] = make_float4(px, py, pz, fmaf(pz, pz, fmaf(py, py, px*px)));
  }
  __syncthreads();

  const int n = r & (NN - 1);
  const float4 ctr = cand[n];            // ctr.w == csq, bit-identical to stage 1
  const unsigned int d20 = d20g[r];
  int* op = idx_out + (size_t)r * K_NN;
  int cg = 0, ce = 0;

#pragma unroll 4
  for (int k = 0; k < NN / 64; ++k) {
    const int i = k * 64 + lane;
    const float4 c = cand[i];
    const float inner = fmaf(ctr.z, c.z, fmaf(ctr.y, c.y, ctr.x*c.x));
    const float d = 2.0f * inner - ctr.w - c.w;    // bit-identical to stage 1
    const unsigned int u = sortable(d);
    const unsigned long long mb = __ballot(u > d20);
    if (u > d20) op[cg + mbcnt(mb)] = i;
    cg += __popcll(mb);
    const unsigned long long tb = __ballot(u == d20);
    if (tb) {
      if (u == d20) {
        const int pos = ce + mbcnt(tb);
        if (pos < K_NN) tie[w][pos] = i;           // capped: only need <=20
      }
      ce += __popcll(tb);
    }
  }
  if (lane == 0)
    for (int j = 0; cg < K_NN; ++j, ++cg) op[cg] = tie[w][j];
}

// ---------------------------------------------------------------------------
// EdgeConv -> split bf16 planes Ah/Al cols [0,64)
// ---------------------------------------------------------------------------
__global__ __launch_bounds__(256) void edgeconv_kernel(const float* __restrict__ x,
    const int* __restrict__ idx, const float* __restrict__ W0,
    const float* __restrict__ b0, unsigned short* __restrict__ Ahg,
    unsigned short* __restrict__ Alg) {
  const int o  = threadIdx.x & 63;
  const int pt = blockIdx.x * 4 + (threadIdx.x >> 6);
  const int b  = pt >> 11, n = pt & (NN - 1);
  const float* xb = x + (size_t)b * NN * 3;

  const float w0 = W0[o*6+0], w1 = W0[o*6+1], w2 = W0[o*6+2];
  const float w3 = W0[o*6+3], w4 = W0[o*6+4], w5 = W0[o*6+5];
  const float bias = b0[o];
  const float cx = xb[n*3+0], cy = xb[n*3+1], cz = xb[n*3+2];

  const int* ip = idx + (size_t)pt * K_NN;
  float px = 0.f, py = 0.f, pz = 0.f;
  if (o < K_NN) { const int m = ip[o]; px = xb[m*3+0]; py = xb[m*3+1]; pz = xb[m*3+2]; }

  float best = NEG_INF;
#pragma unroll
  for (int k = 0; k < K_NN; ++k) {
    const float ax = __shfl(px, k, 64), ay = __shfl(py, k, 64), az = __shfl(pz, k, 64);
    float h = w0 * (ax - cx);
    h = fmaf(w1, ay - cy, h);
    h = fmaf(w2, az - cz, h);
    h = fmaf(w3, cx, h);
    h = fmaf(w4, cy, h);
    h = fmaf(w5, cz, h);
    h += bias;
    h = (h > 0.f) ? h : 0.2f * h;
    best = fmaxf(best, h);
  }
  split_store(best, &Ahg[(size_t)pt * CATC + o], &Alg[(size_t)pt * CATC + o]);
}

// ---------------------------------------------------------------------------
// pool (max over kNN graph) + 1x1 conv + leaky relu.
// Round 10: NO occupancy bound (round 9's launch_bounds(256,4) drove the
// allocator to 64 VGPR + 1.65 GB scratch spill). Register pressure reduced
// STRUCTURALLY instead: 4 channels/thread (uint2 h + uint2 l per neighbor,
// 8B coalesced loads, mv[4] accumulators) -> ~60-70 VGPR spill-free.
// XCD-batch swizzle retained (FETCH 61.6->10MB verified in round 8).
// ---------------------------------------------------------------------------
template<int CIN, int COUT, int PTS>
__global__ __launch_bounds__(256) void pool_mlp_kernel(
    unsigned short* __restrict__ Ahg, unsigned short* __restrict__ Alg,
    const int* __restrict__ idx, const float* __restrict__ W,
    const float* __restrict__ bias, int coff_in, int coff_out) {
  __shared__ float pooled[PTS][CIN + 4];   // rows 16B-aligned (CIN+4 mult of 4)
  __shared__ int sidx[PTS][K_NN];

  constexpr int BPB = NN / PTS;            // blocks per batch
  const int bid  = blockIdx.x;
  const int xcd  = bid & 7;
  const int s    = bid >> 3;
  const int b    = xcd * 2 + s / BPB;      // 2 batches per XCD
  const int inner= s % BPB;
  const int pt0  = b * NN + inner * PTS;

  for (int t = threadIdx.x; t < PTS * K_NN; t += 256)
    sidx[t / K_NN][t % K_NN] = idx[(size_t)pt0 * K_NN + t];
  __syncthreads();

  // ---- gather-max: 4 channels per thread, uint2 (bf16x4) loads ----
  constexpr int CG = CIN / 4;              // threads per point
  static_assert(PTS * CG == 256, "gather must use all 256 threads");
  {
    const int p  = threadIdx.x / CG;
    const int c4 = threadIdx.x % CG;
    const size_t base = (size_t)b * NN * CATC + coff_in + c4 * 4;
    float mv0 = NEG_INF, mv1 = NEG_INF, mv2 = NEG_INF, mv3 = NEG_INF;
#pragma unroll 2
    for (int k = 0; k < K_NN; ++k) {
      const size_t a = base + (size_t)sidx[p][k] * CATC;
      const uint2 h = *(const uint2*)(Ahg + a);
      const uint2 l = *(const uint2*)(Alg + a);
      mv0 = fmaxf(mv0, __uint_as_float(h.x << 16)        + __uint_as_float(l.x << 16));
      mv1 = fmaxf(mv1, __uint_as_float(h.x & 0xFFFF0000u) + __uint_as_float(l.x & 0xFFFF0000u));
      mv2 = fmaxf(mv2, __uint_as_float(h.y << 16)        + __uint_as_float(l.y << 16));
      mv3 = fmaxf(mv3, __uint_as_float(h.y & 0xFFFF0000u) + __uint_as_float(l.y & 0xFFFF0000u));
    }
    *(float4*)&pooled[p][c4 * 4] = make_float4(mv0, mv1, mv2, mv3);
  }
  __syncthreads();

  // ---- 1x1 conv + act + split store ----
  for (int t = threadIdx.x; t < PTS * COUT; t += 256) {
    const int p = t / COUT, o = t % COUT;
    const float4* pp = (const float4*)&pooled[p][0];
    const float4* wp = (const float4*)(W + (size_t)o * CIN);
    float acc = 0.f;
#pragma unroll
    for (int c4 = 0; c4 < CIN / 4; ++c4) {
      const float4 pv = pp[c4], wv = wp[c4];
      acc = fmaf(pv.x, wv.x, acc);
      acc = fmaf(pv.y, wv.y, acc);
      acc = fmaf(pv.z, wv.z, acc);
      acc = fmaf(pv.w, wv.w, acc);
    }
    float h = acc + bias[o];
    h = (h > 0.f) ? h : 0.2f * h;
    const size_t a = (size_t)(pt0 + p) * CATC + coff_out + o;
    split_store(h, &Ahg[a], &Alg[a]);
  }
}

// ---------------------------------------------------------------------------
// Split Wf (1024x512 f32) -> Wh, Wl bf16
// ---------------------------------------------------------------------------
__global__ __launch_bounds__(256) void wsplit_kernel(const float* __restrict__ Wf,
    unsigned short* __restrict__ Wh, unsigned short* __restrict__ Wl) {
  const int t = blockIdx.x * 256 + threadIdx.x;   // 131072 float4 groups
  const float4 v = ((const float4*)Wf)[t];
  ushort4 h4, l4;
  h4.x = f2bf_rn(v.x); l4.x = f2bf_rn(v.x - bf2f(h4.x));
  h4.y = f2bf_rn(v.y); l4.y = f2bf_rn(v.y - bf2f(h4.y));
  h4.z = f2bf_rn(v.z); l4.z = f2bf_rn(v.z - bf2f(h4.z));
  h4.w = f2bf_rn(v.w); l4.w = f2bf_rn(v.w - bf2f(h4.w));
  ((ushort4*)Wh)[t] = h4;
  ((ushort4*)Wl)[t] = l4;
}

// ---------------------------------------------------------------------------
// Final GEMM via bf16x3 MFMA: C = A.Wf^T, running max over rows -> partials.
// ---------------------------------------------------------------------------
__global__ __launch_bounds__(256) void final_gemm_mfma(
    const unsigned short* __restrict__ Ahg, const unsigned short* __restrict__ Alg,
    const unsigned short* __restrict__ Whg, const unsigned short* __restrict__ Wlg,
    float* __restrict__ partials) {
  __shared__ __align__(16) unsigned short AhL[128][40];
  __shared__ __align__(16) unsigned short AlL[128][40];
  __shared__ __align__(16) unsigned short WhL[128][40];
  __shared__ __align__(16) unsigned short WlL[128][40];

  // XCD-aware work decode: each XCD processes whole A-panels.
  const int L     = blockIdx.x + (blockIdx.y << 3) + (blockIdx.z << 7);  // 0..2047
  const int xcd   = L & 7;
  const int q     = L >> 3;        // 0..255
  const int ot    = q & 7;         // col tile, varies fastest within an XCD
  const int s     = q >> 3;        // 0..31 panel slot on this XCD
  const int p     = (s << 3) | xcd;  // panel 0..255
  const int chunk = p & 15;
  const int b     = p >> 4;

  const int tid   = threadIdx.x;
  const int lane  = tid & 63;
  const int w     = tid >> 6;      // wave 0..3
  const int wr    = w >> 1;        // row half (64)
  const int wc    = w & 1;         // col half (64)
  const int fr    = lane & 15;     // fragment row/col within 16
  const int kg    = lane >> 4;     // k-group 0..3

  const int srow = tid >> 1;
  const int shalf = (tid & 1) * 16;
  const size_t arow = ((size_t)(b * NN) + (size_t)chunk * 128 + srow) * CATC;
  const size_t wrow = ((size_t)ot * 128 + srow) * CATC;

  f32x4 acc[4][4];
#pragma unroll
  for (int i = 0; i < 4; ++i)
#pragma unroll
    for (int j = 0; j < 4; ++j) acc[i][j] = (f32x4){0.f, 0.f, 0.f, 0.f};

  // prologue: load tile 0 into named staging regs
  uint4 ra0 = *(const uint4*)(Ahg + arow + shalf);
  uint4 ra1 = *(const uint4*)(Ahg + arow + shalf + 8);
  uint4 ra2 = *(const uint4*)(Alg + arow + shalf);
  uint4 ra3 = *(const uint4*)(Alg + arow + shalf + 8);
  uint4 rw0 = *(const uint4*)(Whg + wrow + shalf);
  uint4 rw1 = *(const uint4*)(Whg + wrow + shalf + 8);
  uint4 rw2 = *(const uint4*)(Wlg + wrow + shalf);
  uint4 rw3 = *(const uint4*)(Wlg + wrow + shalf + 8);

  for (int kt = 0; kt < 16; ++kt) {
    __syncthreads();   // prior iteration's frag reads complete
    *(uint4*)&AhL[srow][shalf]     = ra0;
    *(uint4*)&AhL[srow][shalf + 8] = ra1;
    *(uint4*)&AlL[srow][shalf]     = ra2;
    *(uint4*)&AlL[srow][shalf + 8] = ra3;
    *(uint4*)&WhL[srow][shalf]     = rw0;
    *(uint4*)&WhL[srow][shalf + 8] = rw1;
    *(uint4*)&WlL[srow][shalf]     = rw2;
    *(uint4*)&WlL[srow][shalf + 8] = rw3;
    if (kt < 15) {     // prefetch next tile; latency hides under MFMA phase
      const int k0 = (kt + 1) * 32;
      ra0 = *(const uint4*)(Ahg + arow + k0 + shalf);
      ra1 = *(const uint4*)(Ahg + arow + k0 + shalf + 8);
      ra2 = *(const uint4*)(Alg + arow + k0 + shalf);
      ra3 = *(const uint4*)(Alg + arow + k0 + shalf + 8);
      rw0 = *(const uint4*)(Whg + wrow + k0 + shalf);
      rw1 = *(const uint4*)(Whg + wrow + k0 + shalf + 8);
      rw2 = *(const uint4*)(Wlg + wrow + k0 + shalf);
      rw3 = *(const uint4*)(Wlg + wrow + k0 + shalf + 8);
    }
    __syncthreads();

    bf16x8 ahf[4], alf[4], whf[4], wlf[4];
#pragma unroll
    for (int i = 0; i < 4; ++i) {
      ahf[i] = *(const bf16x8*)&AhL[wr * 64 + i * 16 + fr][kg * 8];
      alf[i] = *(const bf16x8*)&AlL[wr * 64 + i * 16 + fr][kg * 8];
    }
#pragma unroll
    for (int j = 0; j < 4; ++j) {
      whf[j] = *(const bf16x8*)&WhL[wc * 64 + j * 16 + fr][kg * 8];
      wlf[j] = *(const bf16x8*)&WlL[wc * 64 + j * 16 + fr][kg * 8];
    }

#pragma unroll
    for (int i = 0; i < 4; ++i)
#pragma unroll
      for (int j = 0; j < 4; ++j) {
        acc[i][j] = __builtin_amdgcn_mfma_f32_16x16x32_bf16(ahf[i], whf[j], acc[i][j], 0, 0, 0);
        acc[i][j] = __builtin_amdgcn_mfma_f32_16x16x32_bf16(ahf[i], wlf[j], acc[i][j], 0, 0, 0);
        acc[i][j] = __builtin_amdgcn_mfma_f32_16x16x32_bf16(alf[i], whf[j], acc[i][j], 0, 0, 0);
      }
  }

  // ---- epilogue: max over the wave's 64 rows per output col ----
  __syncthreads();                       // all LDS frag reads done
  float* smax = (float*)&AhL[0][0];      // reuse AhL as smax[2][128]
#pragma unroll
  for (int j = 0; j < 4; ++j) {
    float mj = NEG_INF;
#pragma unroll
    for (int i = 0; i < 4; ++i) {
      mj = fmaxf(mj, fmaxf(fmaxf(acc[i][j][0], acc[i][j][1]),
                           fmaxf(acc[i][j][2], acc[i][j][3])));
    }
    mj = fmaxf(mj, __shfl_xor(mj, 16, 64));
    mj = fmaxf(mj, __shfl_xor(mj, 32, 64));
    if (lane < 16) smax[wr * 128 + wc * 64 + j * 16 + fr] = mj;
  }
  __syncthreads();
  if (tid < 128) {
    const float m = fmaxf(smax[tid], smax[128 + tid]);
    partials[((size_t)(b * 16 + chunk)) * 1024 + (size_t)ot * 128 + tid] = m;
  }
}

__global__ __launch_bounds__(256) void final_reduce_kernel(const float* __restrict__ partials,
    const float* __restrict__ bf, float* __restrict__ out) {
  const int t = blockIdx.x * 256 + threadIdx.x;   // 16384
  const int b = t >> 10, o = t & 1023;
  float m = NEG_INF;
#pragma unroll
  for (int c = 0; c < 16; ++c)
    m = fmaxf(m, partials[((size_t)(b * 16 + c)) * 1024 + o]);
  float h = m + bf[o];
  out[t] = (h > 0.f) ? h : 0.2f * h;   // act(max+b) == max(act(.+b)) (monotone)
}

// ---------------------------------------------------------------------------
extern "C" void kernel_launch(void* const* d_in, const int* in_sizes, int n_in,
                              void* d_out, int out_size, void* d_ws, size_t ws_size,
                              hipStream_t stream) {
  (void)in_sizes; (void)n_in; (void)out_size; (void)ws_size;
  const float* x  = (const float*)d_in[0];
  const float* W0 = (const float*)d_in[1];
  const float* b0 = (const float*)d_in[2];
  const float* W1 = (const float*)d_in[3];
  const float* b1 = (const float*)d_in[4];
  const float* W2 = (const float*)d_in[5];
  const float* b2 = (const float*)d_in[6];
  const float* W3 = (const float*)d_in[7];
  const float* b3 = (const float*)d_in[8];
  const float* Wf = (const float*)d_in[9];
  const float* bf = (const float*)d_in[10];
  float* out = (float*)d_out;

  // ws layout (bytes), total 70,778,880:
  //   [0, 2621440)           : idx (int 32768x20) -- dead after pool3;
  //                            Wh [0,1MB) + Wl [1MB,2MB) alias (wsplit after pool3)
  //   [2621440, 23592960)    : cv (u32 160x32768) -- dead after d20, aliased under Ah
  //   [23592960, 23724032)   : d20 (u32 32768)    -- dead after collect, under Ah
  //   [2621440, 36175872)    : Ah bf16[32768][512] (written from edgeconv onward)
  //   [36175872, 69730304)   : Al bf16[32768][512]
  //   [69730304, 70778880)   : partials (float 16*16*1024)
  char* ws = (char*)d_ws;
  int* idx_ws = (int*)ws;
  unsigned short* Wh = (unsigned short*)ws;
  unsigned short* Wl = (unsigned short*)(ws + 1048576);
  unsigned int* cv = (unsigned int*)(ws + 2621440);
  unsigned int* d20g = (unsigned int*)(ws + 23592960);
  unsigned short* Ah = (unsigned short*)(ws + 2621440);
  unsigned short* Al = (unsigned short*)(ws + 36175872);
  float* partials = (float*)(ws + 69730304);

  knn_chunk_kernel<<<BB * 16 * 8, 128, 0, stream>>>(x, cv);
  knn_d20_kernel<<<ROW_G / 64, 64, 0, stream>>>(cv, d20g);
  knn_collect_kernel<<<ROW_G / 4, 256, 0, stream>>>(x, d20g, idx_ws);
  edgeconv_kernel<<<ROW_G / 4, 256, 0, stream>>>(x, idx_ws, W0, b0, Ah, Al);
  pool_mlp_kernel<64, 64, 16><<<BB * (NN / 16), 256, 0, stream>>>(Ah, Al, idx_ws, W1, b1, 0, 64);
  pool_mlp_kernel<64, 128, 16><<<BB * (NN / 16), 256, 0, stream>>>(Ah, Al, idx_ws, W2, b2, 64, 128);
  pool_mlp_kernel<128, 256, 8><<<BB * (NN / 8), 256, 0, stream>>>(Ah, Al, idx_ws, W3, b3, 128, 256);
  wsplit_kernel<<<512, 256, 0, stream>>>(Wf, Wh, Wl);
  final_gemm_mfma<<<dim3(8, 16, BB), 256, 0, stream>>>(Ah, Al, Wh, Wl, partials);
  final_reduce_kernel<<<BB * 1024 / 256, 256, 0, stream>>>(partials, bf, out);
}

// Round 12
// 479.955 us; speedup vs baseline: 2.8291x; 1.0367x over previous
//
#include <hip/hip_runtime.h>

#define K_NN 20
#define NEG_INF (-__builtin_inff())

constexpr int BB   = 16;
constexpr int NN   = 2048;
constexpr int CATC = 512;                 // concat feature width
constexpr int ROW_G = BB * NN;            // 32768 points total

typedef short bf16x8 __attribute__((ext_vector_type(8)));   // 8 bf16 = 4 VGPR
typedef float f32x4  __attribute__((ext_vector_type(4)));

// ---------------- bf16 split helpers (hi = rn(a), lo = rn(a - hi)) ----------
__device__ __forceinline__ unsigned short f2bf_rn(float f) {
  unsigned int u = __float_as_uint(f);
  unsigned int r = u + 0x7FFFu + ((u >> 16) & 1u);
  return (unsigned short)(r >> 16);
}
__device__ __forceinline__ float bf2f(unsigned short h) {
  return __uint_as_float((unsigned int)h << 16);
}
__device__ __forceinline__ void split_store(float v, unsigned short* ph, unsigned short* pl) {
  const unsigned short h = f2bf_rn(v);
  *ph = h;
  *pl = f2bf_rn(v - bf2f(h));
}

__device__ __forceinline__ int mbcnt(unsigned long long mask) {   // popc(mask & lanes_below)
  return __builtin_amdgcn_mbcnt_hi((unsigned int)(mask >> 32),
         __builtin_amdgcn_mbcnt_lo((unsigned int)mask, 0));
}

// ---------------------------------------------------------------------------
// Branch-free u32 top-20 VALUE network (desc, duplicates kept).
// ---------------------------------------------------------------------------
#define DECL_VALS(INIT) \
  unsigned int v0=INIT,v1=INIT,v2=INIT,v3=INIT,v4=INIT,v5=INIT,v6=INIT,v7=INIT, \
               v8=INIT,v9=INIT,v10=INIT,v11=INIT,v12=INIT,v13=INIT,v14=INIT,    \
               v15=INIT,v16=INIT,v17=INIT,v18=INIT,v19=INIT;

#define INSERT_VAL(x) do {                         \
    v19 = min(v18, max(v19, (x)));                 \
    v18 = min(v17, max(v18, (x)));                 \
    v17 = min(v16, max(v17, (x)));                 \
    v16 = min(v15, max(v16, (x)));                 \
    v15 = min(v14, max(v15, (x)));                 \
    v14 = min(v13, max(v14, (x)));                 \
    v13 = min(v12, max(v13, (x)));                 \
    v12 = min(v11, max(v12, (x)));                 \
    v11 = min(v10, max(v11, (x)));                 \
    v10 = min(v9,  max(v10, (x)));                 \
    v9  = min(v8,  max(v9,  (x)));                 \
    v8  = min(v7,  max(v8,  (x)));                 \
    v7  = min(v6,  max(v7,  (x)));                 \
    v6  = min(v5,  max(v6,  (x)));                 \
    v5  = min(v4,  max(v5,  (x)));                 \
    v4  = min(v3,  max(v4,  (x)));                 \
    v3  = min(v2,  max(v3,  (x)));                 \
    v2  = min(v1,  max(v2,  (x)));                 \
    v1  = min(v0,  max(v1,  (x)));                 \
    v0  = max(v0, (x));                            \
  } while (0)

__device__ __forceinline__ unsigned int sortable(float d) {
  unsigned int ub = __float_as_uint(d);
  return (ub & 0x80000000u) ? ~ub : (ub | 0x80000000u);
}

// ---------------------------------------------------------------------------
// kNN stage 1: per (batch, row-tile 128, candidate-chunk 256) top-20 values.
// ---------------------------------------------------------------------------
__global__ __launch_bounds__(128) void knn_chunk_kernel(const float* __restrict__ x,
                                                        unsigned int* __restrict__ cv) {
  __shared__ float4 cand[256];           // {x, y, z, sq} per candidate
  const int bid = blockIdx.x;
  const int ch = bid & 7;          // candidate chunk (8 x 256)
  const int rt = (bid >> 3) & 15;  // row tile (16 x 128)
  const int b  = bid >> 7;         // batch
  const float* xb = x + (size_t)b * NN * 3;

  for (int i = threadIdx.x; i < 256; i += 128) {
    const int m = ch * 256 + i;
    const float px = xb[m*3+0], py = xb[m*3+1], pz = xb[m*3+2];
    cand[i] = make_float4(px, py, pz, fmaf(pz, pz, fmaf(py, py, px*px)));
  }
  __syncthreads();

  const int n = rt * 128 + threadIdx.x;
  const float cx = xb[n*3+0], cy = xb[n*3+1], cz = xb[n*3+2];
  const float csq = fmaf(cz, cz, fmaf(cy, cy, cx*cx));

  DECL_VALS(0u)

#pragma unroll 4
  for (int i = 0; i < 256; ++i) {
    const float4 c = cand[i];
    const float inner = fmaf(cz, c.z, fmaf(cy, c.y, cx*c.x));
    const float d = 2.0f * inner - csq - c.w;      // same op order as reference
    const unsigned int u = sortable(d);
    INSERT_VAL(u);
  }

  const int rowg = b * NN + n;
#define STORE_VAL(i) cv[(size_t)(ch*K_NN + i) * ROW_G + rowg] = v##i;
  STORE_VAL(0) STORE_VAL(1) STORE_VAL(2) STORE_VAL(3) STORE_VAL(4)
  STORE_VAL(5) STORE_VAL(6) STORE_VAL(7) STORE_VAL(8) STORE_VAL(9)
  STORE_VAL(10) STORE_VAL(11) STORE_VAL(12) STORE_VAL(13) STORE_VAL(14)
  STORE_VAL(15) STORE_VAL(16) STORE_VAL(17) STORE_VAL(18) STORE_VAL(19)
#undef STORE_VAL
}

// ---------------------------------------------------------------------------
// kNN stage 2a: merge 8 chunk value-lists -> d20 (20th-largest) per row.
// ---------------------------------------------------------------------------
__global__ __launch_bounds__(64) void knn_d20_kernel(const unsigned int* __restrict__ cv,
                                                     unsigned int* __restrict__ d20g) {
  const int r = blockIdx.x * 64 + threadIdx.x;
#define LOAD_VAL(i) unsigned int v##i = cv[(size_t)i * ROW_G + r];
  LOAD_VAL(0) LOAD_VAL(1) LOAD_VAL(2) LOAD_VAL(3) LOAD_VAL(4)
  LOAD_VAL(5) LOAD_VAL(6) LOAD_VAL(7) LOAD_VAL(8) LOAD_VAL(9)
  LOAD_VAL(10) LOAD_VAL(11) LOAD_VAL(12) LOAD_VAL(13) LOAD_VAL(14)
  LOAD_VAL(15) LOAD_VAL(16) LOAD_VAL(17) LOAD_VAL(18) LOAD_VAL(19)
#undef LOAD_VAL
#pragma unroll 4
  for (int i = K_NN; i < 8 * K_NN; ++i)
    INSERT_VAL(cv[(size_t)i * ROW_G + r]);
  d20g[r] = v19;
}

// ---------------------------------------------------------------------------
// kNN stage 2b: ONE WAVE PER ROW. Rescan 2048 candidates (64/iter), compact
// members (dist > d20, <=19 of them) via ballot; ties (== d20) appended in
// ascending index order (k-major x lane order) -> exact top_k membership.
// ---------------------------------------------------------------------------
__global__ __launch_bounds__(256) void knn_collect_kernel(const float* __restrict__ x,
    const unsigned int* __restrict__ d20g, int* __restrict__ idx_out) {
  __shared__ float4 cand[NN];            // 32 KB, one batch
  __shared__ int tie[4][K_NN];
  const int w = threadIdx.x >> 6, lane = threadIdx.x & 63;
  const int r = blockIdx.x * 4 + w;      // 4 consecutive rows = same batch
  const int b = r >> 11;
  const float* xb = x + (size_t)b * NN * 3;

  for (int i = threadIdx.x; i < NN; i += 256) {
    const float px = xb[i*3+0], py = xb[i*3+1], pz = xb[i*3+2];
    cand[i] = make_float4(px, py, pz, fmaf(pz, pz, fmaf(py, py, px*px)));
  }
  __syncthreads();

  const int n = r & (NN - 1);
  const float4 ctr = cand[n];            // ctr.w == csq, bit-identical to stage 1
  const unsigned int d20 = d20g[r];
  int* op = idx_out + (size_t)r * K_NN;
  int cg = 0, ce = 0;

#pragma unroll 4
  for (int k = 0; k < NN / 64; ++k) {
    const int i = k * 64 + lane;
    const float4 c = cand[i];
    const float inner = fmaf(ctr.z, c.z, fmaf(ctr.y, c.y, ctr.x*c.x));
    const float d = 2.0f * inner - ctr.w - c.w;    // bit-identical to stage 1
    const unsigned int u = sortable(d);
    const unsigned long long mb = __ballot(u > d20);
    if (u > d20) op[cg + mbcnt(mb)] = i;
    cg += __popcll(mb);
    const unsigned long long tb = __ballot(u == d20);
    if (tb) {
      if (u == d20) {
        const int pos = ce + mbcnt(tb);
        if (pos < K_NN) tie[w][pos] = i;           // capped: only need <=20
      }
      ce += __popcll(tb);
    }
  }
  if (lane == 0)
    for (int j = 0; cg < K_NN; ++j, ++cg) op[cg] = tie[w][j];
}

// ---------------------------------------------------------------------------
// EdgeConv -> split bf16 planes Ah/Al cols [0,64)
// ---------------------------------------------------------------------------
__global__ __launch_bounds__(256) void edgeconv_kernel(const float* __restrict__ x,
    const int* __restrict__ idx, const float* __restrict__ W0,
    const float* __restrict__ b0, unsigned short* __restrict__ Ahg,
    unsigned short* __restrict__ Alg) {
  const int o  = threadIdx.x & 63;
  const int pt = blockIdx.x * 4 + (threadIdx.x >> 6);
  const int b  = pt >> 11, n = pt & (NN - 1);
  const float* xb = x + (size_t)b * NN * 3;

  const float w0 = W0[o*6+0], w1 = W0[o*6+1], w2 = W0[o*6+2];
  const float w3 = W0[o*6+3], w4 = W0[o*6+4], w5 = W0[o*6+5];
  const float bias = b0[o];
  const float cx = xb[n*3+0], cy = xb[n*3+1], cz = xb[n*3+2];

  const int* ip = idx + (size_t)pt * K_NN;
  float px = 0.f, py = 0.f, pz = 0.f;
  if (o < K_NN) { const int m = ip[o]; px = xb[m*3+0]; py = xb[m*3+1]; pz = xb[m*3+2]; }

  float best = NEG_INF;
#pragma unroll
  for (int k = 0; k < K_NN; ++k) {
    const float ax = __shfl(px, k, 64), ay = __shfl(py, k, 64), az = __shfl(pz, k, 64);
    float h = w0 * (ax - cx);
    h = fmaf(w1, ay - cy, h);
    h = fmaf(w2, az - cz, h);
    h = fmaf(w3, cx, h);
    h = fmaf(w4, cy, h);
    h = fmaf(w5, cz, h);
    h += bias;
    h = (h > 0.f) ? h : 0.2f * h;
    best = fmaxf(best, h);
  }
  split_store(best, &Ahg[(size_t)pt * CATC + o], &Alg[(size_t)pt * CATC + o]);
}

// ---------------------------------------------------------------------------
// pool (max over kNN graph) + 1x1 conv + leaky relu.
// Round 12: conv phase reordered c4-outer / p-inner. Each thread owns ONE
// output channel o and OPP points; its W row is loaded ONCE and reused
// across all points (was: re-read per point, L1-thrashing -> 4 GB L2 traffic
// for pool3 ~= the whole 109 us). Same (p,o)->thread map, same fma order ->
// bit-identical. Gather + XCD-batch swizzle unchanged (round-11 verified).
// ---------------------------------------------------------------------------
template<int CIN, int COUT, int PTS>
__global__ __launch_bounds__(256) void pool_mlp_kernel(
    unsigned short* __restrict__ Ahg, unsigned short* __restrict__ Alg,
    const int* __restrict__ idx, const float* __restrict__ W,
    const float* __restrict__ bias, int coff_in, int coff_out) {
  __shared__ float pooled[PTS][CIN + 4];   // rows 16B-aligned (CIN+4 mult of 4)
  __shared__ int sidx[PTS][K_NN];

  constexpr int BPB = NN / PTS;            // blocks per batch
  const int bid  = blockIdx.x;
  const int xcd  = bid & 7;
  const int s    = bid >> 3;
  const int b    = xcd * 2 + s / BPB;      // 2 batches per XCD
  const int inner= s % BPB;
  const int pt0  = b * NN + inner * PTS;

  for (int t = threadIdx.x; t < PTS * K_NN; t += 256)
    sidx[t / K_NN][t % K_NN] = idx[(size_t)pt0 * K_NN + t];
  __syncthreads();

  // ---- gather-max: 4 channels per thread, uint2 (bf16x4) loads ----
  constexpr int CG = CIN / 4;              // threads per point
  static_assert(PTS * CG == 256, "gather must use all 256 threads");
  {
    const int p  = threadIdx.x / CG;
    const int c4 = threadIdx.x % CG;
    const size_t base = (size_t)b * NN * CATC + coff_in + c4 * 4;
    float mv0 = NEG_INF, mv1 = NEG_INF, mv2 = NEG_INF, mv3 = NEG_INF;
#pragma unroll 2
    for (int k = 0; k < K_NN; ++k) {
      const size_t a = base + (size_t)sidx[p][k] * CATC;
      const uint2 h = *(const uint2*)(Ahg + a);
      const uint2 l = *(const uint2*)(Alg + a);
      mv0 = fmaxf(mv0, __uint_as_float(h.x << 16)        + __uint_as_float(l.x << 16));
      mv1 = fmaxf(mv1, __uint_as_float(h.x & 0xFFFF0000u) + __uint_as_float(l.x & 0xFFFF0000u));
      mv2 = fmaxf(mv2, __uint_as_float(h.y << 16)        + __uint_as_float(l.y << 16));
      mv3 = fmaxf(mv3, __uint_as_float(h.y & 0xFFFF0000u) + __uint_as_float(l.y & 0xFFFF0000u));
    }
    *(float4*)&pooled[p][c4 * 4] = make_float4(mv0, mv1, mv2, mv3);
  }
  __syncthreads();

  // ---- 1x1 conv + act + split store: c4-outer, p-inner (W row hoisted) ----
  constexpr int OPP = PTS * COUT / 256;    // points per thread
  constexpr int PSTRIDE = 256 / COUT;      // p step between this thread's points
  {
    const int o  = threadIdx.x % COUT;
    const int p0 = threadIdx.x / COUT;
    const float4* wp = (const float4*)(W + (size_t)o * CIN);
    float acc[OPP];
#pragma unroll
    for (int i = 0; i < OPP; ++i) acc[i] = 0.f;
#pragma unroll 4
    for (int c4 = 0; c4 < CIN / 4; ++c4) {
      const float4 wv = wp[c4];
#pragma unroll
      for (int i = 0; i < OPP; ++i) {
        const float4 pv = *(const float4*)&pooled[p0 + i * PSTRIDE][c4 * 4];
        acc[i] = fmaf(pv.x, wv.x, acc[i]);
        acc[i] = fmaf(pv.y, wv.y, acc[i]);
        acc[i] = fmaf(pv.z, wv.z, acc[i]);
        acc[i] = fmaf(pv.w, wv.w, acc[i]);
      }
    }
    const float bo = bias[o];
#pragma unroll
    for (int i = 0; i < OPP; ++i) {
      float h = acc[i] + bo;
      h = (h > 0.f) ? h : 0.2f * h;
      const size_t a = (size_t)(pt0 + p0 + i * PSTRIDE) * CATC + coff_out + o;
      split_store(h, &Ahg[a], &Alg[a]);
    }
  }
}

// ---------------------------------------------------------------------------
// Split Wf (1024x512 f32) -> Wh, Wl bf16
// ---------------------------------------------------------------------------
__global__ __launch_bounds__(256) void wsplit_kernel(const float* __restrict__ Wf,
    unsigned short* __restrict__ Wh, unsigned short* __restrict__ Wl) {
  const int t = blockIdx.x * 256 + threadIdx.x;   // 131072 float4 groups
  const float4 v = ((const float4*)Wf)[t];
  ushort4 h4, l4;
  h4.x = f2bf_rn(v.x); l4.x = f2bf_rn(v.x - bf2f(h4.x));
  h4.y = f2bf_rn(v.y); l4.y = f2bf_rn(v.y - bf2f(h4.y));
  h4.z = f2bf_rn(v.z); l4.z = f2bf_rn(v.z - bf2f(h4.z));
  h4.w = f2bf_rn(v.w); l4.w = f2bf_rn(v.w - bf2f(h4.w));
  ((ushort4*)Wh)[t] = h4;
  ((ushort4*)Wl)[t] = l4;
}

// ---------------------------------------------------------------------------
// Final GEMM via bf16x3 MFMA: C = A.Wf^T, running max over rows -> partials.
// ---------------------------------------------------------------------------
__global__ __launch_bounds__(256) void final_gemm_mfma(
    const unsigned short* __restrict__ Ahg, const unsigned short* __restrict__ Alg,
    const unsigned short* __restrict__ Whg, const unsigned short* __restrict__ Wlg,
    float* __restrict__ partials) {
  __shared__ __align__(16) unsigned short AhL[128][40];
  __shared__ __align__(16) unsigned short AlL[128][40];
  __shared__ __align__(16) unsigned short WhL[128][40];
  __shared__ __align__(16) unsigned short WlL[128][40];

  // XCD-aware work decode: each XCD processes whole A-panels.
  const int L     = blockIdx.x + (blockIdx.y << 3) + (blockIdx.z << 7);  // 0..2047
  const int xcd   = L & 7;
  const int q     = L >> 3;        // 0..255
  const int ot    = q & 7;         // col tile, varies fastest within an XCD
  const int s     = q >> 3;        // 0..31 panel slot on this XCD
  const int p     = (s << 3) | xcd;  // panel 0..255
  const int chunk = p & 15;
  const int b     = p >> 4;

  const int tid   = threadIdx.x;
  const int lane  = tid & 63;
  const int w     = tid >> 6;      // wave 0..3
  const int wr    = w >> 1;        // row half (64)
  const int wc    = w & 1;         // col half (64)
  const int fr    = lane & 15;     // fragment row/col within 16
  const int kg    = lane >> 4;     // k-group 0..3

  const int srow = tid >> 1;
  const int shalf = (tid & 1) * 16;
  const size_t arow = ((size_t)(b * NN) + (size_t)chunk * 128 + srow) * CATC;
  const size_t wrow = ((size_t)ot * 128 + srow) * CATC;

  f32x4 acc[4][4];
#pragma unroll
  for (int i = 0; i < 4; ++i)
#pragma unroll
    for (int j = 0; j < 4; ++j) acc[i][j] = (f32x4){0.f, 0.f, 0.f, 0.f};

  // prologue: load tile 0 into named staging regs
  uint4 ra0 = *(const uint4*)(Ahg + arow + shalf);
  uint4 ra1 = *(const uint4*)(Ahg + arow + shalf + 8);
  uint4 ra2 = *(const uint4*)(Alg + arow + shalf);
  uint4 ra3 = *(const uint4*)(Alg + arow + shalf + 8);
  uint4 rw0 = *(const uint4*)(Whg + wrow + shalf);
  uint4 rw1 = *(const uint4*)(Whg + wrow + shalf + 8);
  uint4 rw2 = *(const uint4*)(Wlg + wrow + shalf);
  uint4 rw3 = *(const uint4*)(Wlg + wrow + shalf + 8);

  for (int kt = 0; kt < 16; ++kt) {
    __syncthreads();   // prior iteration's frag reads complete
    *(uint4*)&AhL[srow][shalf]     = ra0;
    *(uint4*)&AhL[srow][shalf + 8] = ra1;
    *(uint4*)&AlL[srow][shalf]     = ra2;
    *(uint4*)&AlL[srow][shalf + 8] = ra3;
    *(uint4*)&WhL[srow][shalf]     = rw0;
    *(uint4*)&WhL[srow][shalf + 8] = rw1;
    *(uint4*)&WlL[srow][shalf]     = rw2;
    *(uint4*)&WlL[srow][shalf + 8] = rw3;
    if (kt < 15) {     // prefetch next tile; latency hides under MFMA phase
      const int k0 = (kt + 1) * 32;
      ra0 = *(const uint4*)(Ahg + arow + k0 + shalf);
      ra1 = *(const uint4*)(Ahg + arow + k0 + shalf + 8);
      ra2 = *(const uint4*)(Alg + arow + k0 + shalf);
      ra3 = *(const uint4*)(Alg + arow + k0 + shalf + 8);
      rw0 = *(const uint4*)(Whg + wrow + k0 + shalf);
      rw1 = *(const uint4*)(Whg + wrow + k0 + shalf + 8);
      rw2 = *(const uint4*)(Wlg + wrow + k0 + shalf);
      rw3 = *(const uint4*)(Wlg + wrow + k0 + shalf + 8);
    }
    __syncthreads();

    bf16x8 ahf[4], alf[4], whf[4], wlf[4];
#pragma unroll
    for (int i = 0; i < 4; ++i) {
      ahf[i] = *(const bf16x8*)&AhL[wr * 64 + i * 16 + fr][kg * 8];
      alf[i] = *(const bf16x8*)&AlL[wr * 64 + i * 16 + fr][kg * 8];
    }
#pragma unroll
    for (int j = 0; j < 4; ++j) {
      whf[j] = *(const bf16x8*)&WhL[wc * 64 + j * 16 + fr][kg * 8];
      wlf[j] = *(const bf16x8*)&WlL[wc * 64 + j * 16 + fr][kg * 8];
    }

#pragma unroll
    for (int i = 0; i < 4; ++i)
#pragma unroll
      for (int j = 0; j < 4; ++j) {
        acc[i][j] = __builtin_amdgcn_mfma_f32_16x16x32_bf16(ahf[i], whf[j], acc[i][j], 0, 0, 0);
        acc[i][j] = __builtin_amdgcn_mfma_f32_16x16x32_bf16(ahf[i], wlf[j], acc[i][j], 0, 0, 0);
        acc[i][j] = __builtin_amdgcn_mfma_f32_16x16x32_bf16(alf[i], whf[j], acc[i][j], 0, 0, 0);
      }
  }

  // ---- epilogue: max over the wave's 64 rows per output col ----
  __syncthreads();                       // all LDS frag reads done
  float* smax = (float*)&AhL[0][0];      // reuse AhL as smax[2][128]
#pragma unroll
  for (int j = 0; j < 4; ++j) {
    float mj = NEG_INF;
#pragma unroll
    for (int i = 0; i < 4; ++i) {
      mj = fmaxf(mj, fmaxf(fmaxf(acc[i][j][0], acc[i][j][1]),
                           fmaxf(acc[i][j][2], acc[i][j][3])));
    }
    mj = fmaxf(mj, __shfl_xor(mj, 16, 64));
    mj = fmaxf(mj, __shfl_xor(mj, 32, 64));
    if (lane < 16) smax[wr * 128 + wc * 64 + j * 16 + fr] = mj;
  }
  __syncthreads();
  if (tid < 128) {
    const float m = fmaxf(smax[tid], smax[128 + tid]);
    partials[((size_t)(b * 16 + chunk)) * 1024 + (size_t)ot * 128 + tid] = m;
  }
}

__global__ __launch_bounds__(256) void final_reduce_kernel(const float* __restrict__ partials,
    const float* __restrict__ bf, float* __restrict__ out) {
  const int t = blockIdx.x * 256 + threadIdx.x;   // 16384
  const int b = t >> 10, o = t & 1023;
  float m = NEG_INF;
#pragma unroll
  for (int c = 0; c < 16; ++c)
    m = fmaxf(m, partials[((size_t)(b * 16 + c)) * 1024 + o]);
  float h = m + bf[o];
  out[t] = (h > 0.f) ? h : 0.2f * h;   // act(max+b) == max(act(.+b)) (monotone)
}

// ---------------------------------------------------------------------------
extern "C" void kernel_launch(void* const* d_in, const int* in_sizes, int n_in,
                              void* d_out, int out_size, void* d_ws, size_t ws_size,
                              hipStream_t stream) {
  (void)in_sizes; (void)n_in; (void)out_size; (void)ws_size;
  const float* x  = (const float*)d_in[0];
  const float* W0 = (const float*)d_in[1];
  const float* b0 = (const float*)d_in[2];
  const float* W1 = (const float*)d_in[3];
  const float* b1 = (const float*)d_in[4];
  const float* W2 = (const float*)d_in[5];
  const float* b2 = (const float*)d_in[6];
  const float* W3 = (const float*)d_in[7];
  const float* b3 = (const float*)d_in[8];
  const float* Wf = (const float*)d_in[9];
  const float* bf = (const float*)d_in[10];
  float* out = (float*)d_out;

  // ws layout (bytes), total 70,778,880:
  //   [0, 2621440)           : idx (int 32768x20) -- dead after pool3;
  //                            Wh [0,1MB) + Wl [1MB,2MB) alias (wsplit after pool3)
  //   [2621440, 23592960)    : cv (u32 160x32768) -- dead after d20, aliased under Ah
  //   [23592960, 23724032)   : d20 (u32 32768)    -- dead after collect, under Ah
  //   [2621440, 36175872)    : Ah bf16[32768][512] (written from edgeconv onward)
  //   [36175872, 69730304)   : Al bf16[32768][512]
  //   [69730304, 70778880)   : partials (float 16*16*1024)
  char* ws = (char*)d_ws;
  int* idx_ws = (int*)ws;
  unsigned short* Wh = (unsigned short*)ws;
  unsigned short* Wl = (unsigned short*)(ws + 1048576);
  unsigned int* cv = (unsigned int*)(ws + 2621440);
  unsigned int* d20g = (unsigned int*)(ws + 23592960);
  unsigned short* Ah = (unsigned short*)(ws + 2621440);
  unsigned short* Al = (unsigned short*)(ws + 36175872);
  float* partials = (float*)(ws + 69730304);

  knn_chunk_kernel<<<BB * 16 * 8, 128, 0, stream>>>(x, cv);
  knn_d20_kernel<<<ROW_G / 64, 64, 0, stream>>>(cv, d20g);
  knn_collect_kernel<<<ROW_G / 4, 256, 0, stream>>>(x, d20g, idx_ws);
  edgeconv_kernel<<<ROW_G / 4, 256, 0, stream>>>(x, idx_ws, W0, b0, Ah, Al);
  pool_mlp_kernel<64, 64, 16><<<BB * (NN / 16), 256, 0, stream>>>(Ah, Al, idx_ws, W1, b1, 0, 64);
  pool_mlp_kernel<64, 128, 16><<<BB * (NN / 16), 256, 0, stream>>>(Ah, Al, idx_ws, W2, b2, 64, 128);
  pool_mlp_kernel<128, 256, 8><<<BB * (NN / 8), 256, 0, stream>>>(Ah, Al, idx_ws, W3, b3, 128, 256);
  wsplit_kernel<<<512, 256, 0, stream>>>(Wf, Wh, Wl);
  final_gemm_mfma<<<dim3(8, 16, BB), 256, 0, stream>>>(Ah, Al, Wh, Wl, partials);
  final_reduce_kernel<<<BB * 1024 / 256, 256, 0, stream>>>(partials, bf, out);
}